// Round 1
// baseline (1879077.930 us; speedup 1.0000x reference)
//
#include <hip/hip_runtime.h>
#include <math.h>

#define NN_ 128   // batch
#define TT  100   // time steps
#define SS  128   // state dim
#define AA  32    // action dim
#define LL  1024  // hidden (= Z)
#define NBLK 264  // 4 groups x 66; group g = bid&3 -> XCDs {g, g+4} under round-robin dispatch
#define HRS  1034 // LDS h-stage row stride (bf16): max 2-way bank aliasing (free)

// Sync design (this round): subgroup = (g, lbid&1) = the 33 blocks expected on ONE XCD.
// Locality is VERIFIED at runtime (XCC_ID roster mask); if a subgroup is not co-resident
// on one XCD it independently falls back to agent(LLC)-scope ops -> always correct.
// Producers dual-store h (plain->own L2, sc0sc1->LLC); same-XCD readers use sc0-only
// (L1-bypass, L2-hit) loads; cross-XCD readers use agent loads. Barrier = packed slot
// line + leader (head block) + single cross-XCD flag handshake + local release flag.

typedef __attribute__((ext_vector_type(8))) short bf16x8;   // 8 bf16 in 4 VGPRs
typedef __attribute__((ext_vector_type(4))) float f32x4;
typedef __attribute__((ext_vector_type(4))) int   i32x4;

__device__ __forceinline__ float sigmoidf_(float x) { return 1.0f / (1.0f + expf(-x)); }
__device__ __forceinline__ unsigned short f2bf(float x) {
    union { float f; unsigned u; } v; v.f = x;
    return (unsigned short)((v.u + 0x7fffu + ((v.u >> 16) & 1u)) >> 16);   // RNE
}

// ---- scope-tiered access helpers -------------------------------------------
// sc0      : L1-bypass, served by this XCD's L2 (XCD-local coherence)
// sc0 sc1  : L1+L2 bypass, served by the LLC    (device/agent coherence)
__device__ __forceinline__ i32x4 ldg16l(const unsigned short* p) {
    i32x4 r; asm volatile("global_load_dwordx4 %0, %1, off sc0"
                          : "=v"(r) : "v"((unsigned long long)p));
    return r;
}
__device__ __forceinline__ i32x4 ldg16g(const unsigned short* p) {
    i32x4 r; asm volatile("global_load_dwordx4 %0, %1, off sc0 sc1"
                          : "=v"(r) : "v"((unsigned long long)p));
    return r;
}
__device__ __forceinline__ void stg16_dual(unsigned short* p, bf16x8 v) {
    union { bf16x8 h; i32x4 i; } u; u.h = v;
    asm volatile("global_store_dwordx4 %0, %1, off sc0 sc1"
                 :: "v"((unsigned long long)p), "v"(u.i) : "memory");
    *(bf16x8*)p = v;        // duplicate into producer-XCD L2 (vector L1 is write-through)
}
__device__ __forceinline__ void st16_dual(unsigned short* p, unsigned short v) {
    asm volatile("global_store_short %0, %1, off sc0 sc1"
                 :: "v"((unsigned long long)p), "v"((unsigned)v) : "memory");
    *p = v;
}
__device__ __forceinline__ void st32f(int* p, int v, bool loc) {
    if (loc) asm volatile("global_store_dword %0, %1, off"
                          :: "v"((unsigned long long)p), "v"(v) : "memory");
    else     asm volatile("global_store_dword %0, %1, off sc0 sc1"
                          :: "v"((unsigned long long)p), "v"(v) : "memory");
}
__device__ __forceinline__ int ld32f(const int* p, bool loc) {
    int r;
    if (loc) asm volatile("global_load_dword %0, %1, off sc0\n\ts_waitcnt vmcnt(0)"
                          : "=v"(r) : "v"((unsigned long long)p) : "memory");
    else     asm volatile("global_load_dword %0, %1, off sc0 sc1\n\ts_waitcnt vmcnt(0)"
                          : "=v"(r) : "v"((unsigned long long)p) : "memory");
    return r;
}

struct PParams {
    const float *s, *a, *s_next, *eps;
    const float *eWih, *eWhh, *ebih, *ebhh;
    const float *muW, *mub, *lvW, *lvb;
    const float *dWih, *dWhh, *dbih, *dbhh;
    const float *d1W, *d1b, *d2W, *d2b, *d3W, *d3b;
    int *bar;
    int *endv, *startv, *limitv;
    unsigned short *hencAb, *hencBb, *hdecAb, *hdecBb, *hf_bf;
    unsigned short *eWih_b, *eWhh_b, *dWih_b, *dWhh_b, *mlW_b, *xenc_b, *adec_b;
    unsigned short *d1Wb, *d2Wb, *d3Wb;
    float *loss;
};

// ---------------------------------------------------------------- h-tile stages
// jb remap makes cols 0-511 owned by even lbid (XCD g), 512-1023 by odd (XCD g+4).
// chunk = tid&127 (constant over k!), so waves 0,2 read cols 0-511 and waves 1,3
// read cols 512-1023: the local/remote split is wave-uniform. `loc` = this wave's
// columns were produced on my XCD and my subgroup verified co-residency.
__device__ __forceinline__ void stage_h32(const unsigned short* __restrict__ src, int n0,
                                          unsigned short* hstage, int tid, bool loc) {
    i32x4 v[16];
    if (loc) {
        #pragma unroll
        for (int k = 0; k < 16; ++k) {
            const int ci = tid + (k << 8);
            v[k] = ldg16l(src + (size_t)(n0 + (ci >> 7)) * LL + (ci & 127) * 8);
        }
    } else {
        #pragma unroll
        for (int k = 0; k < 16; ++k) {
            const int ci = tid + (k << 8);
            v[k] = ldg16g(src + (size_t)(n0 + (ci >> 7)) * LL + (ci & 127) * 8);
        }
    }
    asm volatile("s_waitcnt vmcnt(0)" ::: "memory");
    #pragma unroll
    for (int k = 0; k < 16; ++k) {
        const int ci = tid + (k << 8);
        *(i32x4*)&hstage[(ci >> 7) * HRS + (ci & 127) * 8] = v[k];
    }
}
__device__ __forceinline__ void stage_h16(const unsigned short* __restrict__ src, int n0,
                                          unsigned short* hstage, int tid, bool loc) {
    i32x4 v[8];
    if (loc) {
        #pragma unroll
        for (int k = 0; k < 8; ++k) {
            const int ci = tid + (k << 8);
            v[k] = ldg16l(src + (size_t)(n0 + (ci >> 7)) * LL + (ci & 127) * 8);
        }
    } else {
        #pragma unroll
        for (int k = 0; k < 8; ++k) {
            const int ci = tid + (k << 8);
            v[k] = ldg16g(src + (size_t)(n0 + (ci >> 7)) * LL + (ci & 127) * 8);
        }
    }
    asm volatile("s_waitcnt vmcnt(0)" ::: "memory");
    #pragma unroll
    for (int k = 0; k < 8; ++k) {
        const int ci = tid + (k << 8);
        *(i32x4*)&hstage[(ci >> 7) * HRS + (ci & 127) * 8] = v[k];
    }
}

// ---------------------------------------------------------------- barriers
// Global (phase 0 only, unchanged): bar[g*16] 8 counters; [128] master; [132] broken;
// [144+b*16] flags.
__device__ void gbar_global(int* bar, int bid, int tid, int gen) {
    __syncthreads();
    if (tid == 0) {
        if (__hip_atomic_load(bar + 132, __ATOMIC_RELAXED, __HIP_MEMORY_SCOPE_AGENT) == 0) {
            const int g = bid & 7;
            int pos = __hip_atomic_fetch_add(bar + g * 16, 1, __ATOMIC_RELAXED, __HIP_MEMORY_SCOPE_AGENT);
            if (pos + 1 == (NBLK / 8) * gen) {
                int mp = __hip_atomic_fetch_add(bar + 128, 1, __ATOMIC_RELAXED, __HIP_MEMORY_SCOPE_AGENT);
                if (mp + 1 == 8 * gen) {
                    for (int b = 0; b < NBLK; ++b)
                        __hip_atomic_store(bar + 144 + b * 16, gen, __ATOMIC_RELAXED, __HIP_MEMORY_SCOPE_AGENT);
                }
            }
            int it = 0;
            while (__hip_atomic_load(bar + 144 + bid * 16, __ATOMIC_RELAXED, __HIP_MEMORY_SCOPE_AGENT) < gen) {
                __builtin_amdgcn_s_sleep(1);
                if (++it > 4000000) {
                    __hip_atomic_store(bar + 132, 1, __ATOMIC_RELAXED, __HIP_MEMORY_SCOPE_AGENT);
                    break;
                }
            }
        }
    }
    __syncthreads();
}

// Per-step barrier. bar int layout:
//   4608 + (g*2+half)*96 : [0..31] slot line (one 128B line), [32] release flag
//   5376 + g*64 + half*32: cross-XCD pair flag (always agent scope)
//   5632 + (g*2+half)*32 : XCC roster mask
// Matmul block lbid<64: slot idx = lbid>>1 within (g, lbid&1). Head blocks (64,65)
// are the leaders of their halves (idle in encoder, light in decoder).
__device__ void gbar2(int* bar, int g, int half, int lbid, bool loc, int tid, int gen) {
    __syncthreads();   // drains this block's h stores (vmcnt(0) before s_barrier)
    if (tid == 0) {
        int* sg  = bar + 4608 + (g * 2 + half) * 96;
        int* rel = sg + 32;
        int* pme = bar + 5376 + g * 64 + half * 32;
        int* pot = bar + 5376 + g * 64 + (half ^ 1) * 32;
        int* brk = bar + 132;
        if (lbid >= 64) {
            // ---- leader: wait all 32 local slots >= gen (one batched line read)
            i32x4 s0, s1, s2, s3, s4, s5, s6, s7;
            const unsigned long long sga = (unsigned long long)sg;
            int it = 0;
            for (;;) {
                if (loc) {
                    asm volatile(
                        "global_load_dwordx4 %0, %8, off sc0\n\t"
                        "global_load_dwordx4 %1, %8, off offset:16 sc0\n\t"
                        "global_load_dwordx4 %2, %8, off offset:32 sc0\n\t"
                        "global_load_dwordx4 %3, %8, off offset:48 sc0\n\t"
                        "global_load_dwordx4 %4, %8, off offset:64 sc0\n\t"
                        "global_load_dwordx4 %5, %8, off offset:80 sc0\n\t"
                        "global_load_dwordx4 %6, %8, off offset:96 sc0\n\t"
                        "global_load_dwordx4 %7, %8, off offset:112 sc0\n\t"
                        "s_waitcnt vmcnt(0)"
                        : "=v"(s0), "=v"(s1), "=v"(s2), "=v"(s3),
                          "=v"(s4), "=v"(s5), "=v"(s6), "=v"(s7)
                        : "v"(sga) : "memory");
                } else {
                    asm volatile(
                        "global_load_dwordx4 %0, %8, off sc0 sc1\n\t"
                        "global_load_dwordx4 %1, %8, off offset:16 sc0 sc1\n\t"
                        "global_load_dwordx4 %2, %8, off offset:32 sc0 sc1\n\t"
                        "global_load_dwordx4 %3, %8, off offset:48 sc0 sc1\n\t"
                        "global_load_dwordx4 %4, %8, off offset:64 sc0 sc1\n\t"
                        "global_load_dwordx4 %5, %8, off offset:80 sc0 sc1\n\t"
                        "global_load_dwordx4 %6, %8, off offset:96 sc0 sc1\n\t"
                        "global_load_dwordx4 %7, %8, off offset:112 sc0 sc1\n\t"
                        "s_waitcnt vmcnt(0)"
                        : "=v"(s0), "=v"(s1), "=v"(s2), "=v"(s3),
                          "=v"(s4), "=v"(s5), "=v"(s6), "=v"(s7)
                        : "v"(sga) : "memory");
                }
                int mn = s0[0];
                mn = min(mn, s0[1]); mn = min(mn, s0[2]); mn = min(mn, s0[3]);
                mn = min(mn, s1[0]); mn = min(mn, s1[1]); mn = min(mn, s1[2]); mn = min(mn, s1[3]);
                mn = min(mn, s2[0]); mn = min(mn, s2[1]); mn = min(mn, s2[2]); mn = min(mn, s2[3]);
                mn = min(mn, s3[0]); mn = min(mn, s3[1]); mn = min(mn, s3[2]); mn = min(mn, s3[3]);
                mn = min(mn, s4[0]); mn = min(mn, s4[1]); mn = min(mn, s4[2]); mn = min(mn, s4[3]);
                mn = min(mn, s5[0]); mn = min(mn, s5[1]); mn = min(mn, s5[2]); mn = min(mn, s5[3]);
                mn = min(mn, s6[0]); mn = min(mn, s6[1]); mn = min(mn, s6[2]); mn = min(mn, s6[3]);
                mn = min(mn, s7[0]); mn = min(mn, s7[1]); mn = min(mn, s7[2]); mn = min(mn, s7[3]);
                if (mn >= gen) break;
                __builtin_amdgcn_s_sleep(1);
                if (((++it) & 65535) == 0) {
                    if (ld32f(brk, false)) break;
                    if (it > 2000000) { st32f(brk, 1, false); break; }
                }
            }
            // ---- cross-XCD pair handshake (the one remaining LLC round trip)
            st32f(pme, gen, false);
            it = 0;
            while (ld32f(pot, false) < gen) {
                __builtin_amdgcn_s_sleep(1);
                if (((++it) & 65535) == 0) {
                    if (ld32f(brk, false)) break;
                    if (it > 2000000) { st32f(brk, 1, false); break; }
                }
            }
            // ---- local release
            st32f(rel, gen, loc);
        } else {
            st32f(sg + (lbid >> 1), gen, loc);   // arrive
            int it = 0;
            while (ld32f(rel, loc) < gen) {
                __builtin_amdgcn_s_sleep(1);
                if (((++it) & 65535) == 0) {
                    if (ld32f(brk, false)) break;
                    if (it > 2000000) { st32f(brk, 1, false); break; }
                }
            }
        }
    }
    __syncthreads();
}

// ---------------------------------------------------------------- init (separate launch)
__global__ void init_kernel(int* bar, float* loss) {
    for (int i = threadIdx.x; i < 6144; i += 256) bar[i] = 0;
    if (threadIdx.x == 0) loss[0] = 0.0f;
}

// ---------------------------------------------------------------- GRU step matmul tile
// Per group: 64 blocks x 16 j-cols (3 gates), 32 samples. Waves: nh=w&1 sample-half,
// kh=w>>1 K-half. fp32 h state lives in `hold` regs of kh==0 waves; h stores go out
// dual-scope (L2 + LLC), coalesced 16B via LDS transpose.
template<int XK, bool IS_DEC>
__device__ void gru_tile(const int ng0, const int jb, const int tid, const bool loc,
    const unsigned short* __restrict__ h_bf, unsigned short* __restrict__ ho_bf,
    const unsigned short* __restrict__ Whh_b, const unsigned short* __restrict__ Wih_b,
    const unsigned short* __restrict__ x_bf,
    const float* __restrict__ bih, const float* __restrict__ bhh,
    const int* __restrict__ endv, unsigned short* __restrict__ hf_bf,
    int t, f32x4 (&red)[2][4][64], unsigned short* hstage, f32x4& hold)
{
    const int lane = tid & 63, w = tid >> 6;
    const int nh = w & 1, kh = w >> 1;
    const int m = lane & 15, quad = lane >> 4;
    const int jcol = jb + m;

    stage_h32(h_bf, ng0, hstage, tid, loc);
    __syncthreads();

    f32x4 accr{}, accz{}, acchn{}, accxn{};

    {   // hidden: K = 1024, 32 chunks, split 16/16 across kh; A from LDS
        const int arow = (nh * 16 + m) * HRS + quad * 8;
        const unsigned short* brp = Whh_b + (size_t)(0 * LL + jcol) * LL + quad * 8;
        const unsigned short* bzp = Whh_b + (size_t)(1 * LL + jcol) * LL + quad * 8;
        const unsigned short* bnp = Whh_b + (size_t)(2 * LL + jcol) * LL + quad * 8;
        #pragma unroll 4
        for (int c = kh * 16; c < kh * 16 + 16; ++c) {
            const int k0 = c * 32;
            bf16x8 av = *(const bf16x8*)&hstage[arow + k0];
            bf16x8 br = *(const bf16x8*)(brp + k0);
            bf16x8 bz = *(const bf16x8*)(bzp + k0);
            bf16x8 bn = *(const bf16x8*)(bnp + k0);
            accr  = __builtin_amdgcn_mfma_f32_16x16x32_bf16(av, br, accr, 0, 0, 0);
            accz  = __builtin_amdgcn_mfma_f32_16x16x32_bf16(av, bz, accz, 0, 0, 0);
            acchn = __builtin_amdgcn_mfma_f32_16x16x32_bf16(av, bn, acchn, 0, 0, 0);
        }
    }
    {   // input: K = XK (enc 160, dec 32); read-only -> plain L1/L2-cached loads
        const int XC = XK / 32, XC0 = (XC + 1) / 2;
        const size_t xstride = IS_DEC ? (size_t)(50 * AA) : (size_t)(TT * (SS + AA));
        const unsigned short* xp  = x_bf + (size_t)(ng0 + nh * 16 + m) * xstride + (size_t)t * XK + quad * 8;
        const unsigned short* brp = Wih_b + (size_t)(0 * LL + jcol) * XK + quad * 8;
        const unsigned short* bzp = Wih_b + (size_t)(1 * LL + jcol) * XK + quad * 8;
        const unsigned short* bnp = Wih_b + (size_t)(2 * LL + jcol) * XK + quad * 8;
        #pragma unroll
        for (int c = (kh ? XC0 : 0); c < (kh ? XC : XC0); ++c) {
            const int k0 = c * 32;
            bf16x8 av = *(const bf16x8*)(xp + k0);
            bf16x8 br = *(const bf16x8*)(brp + k0);
            bf16x8 bz = *(const bf16x8*)(bzp + k0);
            bf16x8 bn = *(const bf16x8*)(bnp + k0);
            accr  = __builtin_amdgcn_mfma_f32_16x16x32_bf16(av, br, accr, 0, 0, 0);
            accz  = __builtin_amdgcn_mfma_f32_16x16x32_bf16(av, bz, accz, 0, 0, 0);
            accxn = __builtin_amdgcn_mfma_f32_16x16x32_bf16(av, bn, accxn, 0, 0, 0);
        }
    }
    if (kh == 1) {
        red[nh][0][lane] = accr;  red[nh][1][lane] = accz;
        red[nh][2][lane] = acchn; red[nh][3][lane] = accxn;
    }
    __syncthreads();
    if (kh == 0) {
        accr  += red[nh][0][lane];  accz  += red[nh][1][lane];
        acchn += red[nh][2][lane];  accxn += red[nh][3][lane];
        const float br_  = bih[jcol] + bhh[jcol];
        const float bz_  = bih[LL + jcol] + bhh[LL + jcol];
        const float bxn_ = bih[2 * LL + jcol];
        const float bhn_ = bhh[2 * LL + jcol];
        unsigned short* tr = hstage + nh * (16 * 24);    // wave-private transpose scratch
        #pragma unroll
        for (int i = 0; i < 4; ++i) {
            const int n = ng0 + nh * 16 + quad * 4 + i;  // C layout: row=quad*4+i, col=m
            float r = sigmoidf_(accr[i] + br_);
            float z = sigmoidf_(accz[i] + bz_);
            float g = tanhf(accxn[i] + bxn_ + r * (acchn[i] + bhn_));
            float hn = (1.0f - z) * g + z * hold[i];
            hold[i] = hn;
            unsigned short hb = f2bf(hn);
            tr[(quad * 4 + i) * 24 + m] = hb;            // LDS transpose (wave-lockstep)
            if (!IS_DEC) { if (endv[n] == t) st16_dual(hf_bf + (size_t)n * LL + jcol, hb); }
        }
        // coalesced 16B n-major stores: lanes 0..31 each store 8 bf16, dual-scope
        if (lane < 32) {
            const int nl = lane >> 1, jh = lane & 1;
            bf16x8 vv = *(const bf16x8*)&tr[nl * 24 + jh * 8];
            stg16_dual(ho_bf + (size_t)(ng0 + nh * 16 + nl) * LL + jb + jh * 8, vv);
        }
    }
}

// ---------------------------------------------------------------- reparametrize tile
__device__ void emb_tile(const PParams& P, const int ng0, const int jb, const int tid,
                         const bool loc, f32x4 (&red)[2][4][64], unsigned short* hstage,
                         f32x4& hold)
{
    const int lane = tid & 63, w = tid >> 6;
    const int nh = w & 1, kh = w >> 1;
    const int m = lane & 15, quad = lane >> 4;
    const int jcol = jb + m;

    stage_h32(P.hf_bf, ng0, hstage, tid, loc);
    __syncthreads();

    f32x4 accm{}, accl{};
    const int arow = (nh * 16 + m) * HRS + quad * 8;
    const unsigned short* bmp = P.mlW_b + (size_t)jcol * LL + quad * 8;
    const unsigned short* blp = P.mlW_b + (size_t)(LL + jcol) * LL + quad * 8;
    #pragma unroll 4
    for (int c = kh * 16; c < kh * 16 + 16; ++c) {
        const int k0 = c * 32;
        bf16x8 av = *(const bf16x8*)&hstage[arow + k0];
        bf16x8 bm = *(const bf16x8*)(bmp + k0);
        bf16x8 bl = *(const bf16x8*)(blp + k0);
        accm = __builtin_amdgcn_mfma_f32_16x16x32_bf16(av, bm, accm, 0, 0, 0);
        accl = __builtin_amdgcn_mfma_f32_16x16x32_bf16(av, bl, accl, 0, 0, 0);
    }
    if (kh == 1) { red[nh][0][lane] = accm; red[nh][1][lane] = accl; }
    __syncthreads();
    if (kh == 0) {
        accm += red[nh][0][lane]; accl += red[nh][1][lane];
        unsigned short* tr = hstage + nh * (16 * 24);
        #pragma unroll
        for (int i = 0; i < 4; ++i) {
            const int n = ng0 + nh * 16 + quad * 4 + i;
            float mu = accm[i] + P.mub[jcol];
            float lv = accl[i] + P.lvb[jcol];
            float e = mu + expf(0.5f * lv) * P.eps[(size_t)n * LL + jcol];
            hold[i] = e;
            tr[(quad * 4 + i) * 24 + m] = f2bf(e);
        }
        if (lane < 32) {
            const int nl = lane >> 1, jh = lane & 1;
            bf16x8 vv = *(const bf16x8*)&tr[nl * 24 + jh * 8];
            stg16_dual(P.hdecAb + (size_t)(ng0 + nh * 16 + nl) * LL + jb + jh * 8, vv);
        }
    }
}

// ---------------------------------------------------------------- MFMA decoder head
__device__ void head_tile(const PParams& P, const int n0, const int tid, const bool loc,
                          const unsigned short* __restrict__ h_bf, int ti,
                          unsigned short* hstage, char* shu)
{
    auto& ylds  = *(unsigned short (*)[16][136])(shu);
    auto& y2lds = *(unsigned short (*)[16][72])(shu + 4352);
    float* lred = (float*)(shu + 4352 + 2304);
    const int lane = tid & 63, w = tid >> 6;
    const int m16 = lane & 15, quad = lane >> 4;

    stage_h16(h_bf, n0, hstage, tid, loc);
    __syncthreads();

    // ---- y1: K=1024, 8 j-tiles, wave w -> {2w, 2w+1}
    #pragma unroll
    for (int jt = 0; jt < 2; ++jt) {
        const int c0 = (w * 2 + jt) * 16;
        f32x4 acc{};
        const int abase = m16 * HRS + quad * 8;
        const unsigned short* bp = P.d1Wb + (size_t)(c0 + m16) * LL + quad * 8;
        #pragma unroll 4
        for (int c = 0; c < 32; ++c) {
            bf16x8 av = *(const bf16x8*)&hstage[abase + c * 32];
            bf16x8 bv = *(const bf16x8*)(bp + c * 32);
            acc = __builtin_amdgcn_mfma_f32_16x16x32_bf16(av, bv, acc, 0, 0, 0);
        }
        const float b = P.d1b[c0 + m16];
        #pragma unroll
        for (int i = 0; i < 4; ++i)
            ylds[quad * 4 + i][c0 + m16] = f2bf(fmaxf(acc[i] + b, 0.0f));
    }
    __syncthreads();

    // ---- y2: K=128, wave w -> tile w
    {
        const int c0 = w * 16;
        f32x4 acc{};
        #pragma unroll
        for (int c = 0; c < 4; ++c) {
            bf16x8 av = *(const bf16x8*)&ylds[m16][c * 32 + quad * 8];
            bf16x8 bv = *(const bf16x8*)(P.d2Wb + (size_t)(c0 + m16) * 128 + c * 32 + quad * 8);
            acc = __builtin_amdgcn_mfma_f32_16x16x32_bf16(av, bv, acc, 0, 0, 0);
        }
        const float b = P.d2b[c0 + m16];
        #pragma unroll
        for (int i = 0; i < 4; ++i)
            y2lds[quad * 4 + i][c0 + m16] = f2bf(fmaxf(acc[i] + b, 0.0f));
    }
    __syncthreads();

    // ---- y3: K=64, wave w -> {2w, 2w+1}; fused masked L1
    float lsum = 0.0f;
    #pragma unroll
    for (int jt = 0; jt < 2; ++jt) {
        const int c0 = (w * 2 + jt) * 16;
        f32x4 acc{};
        #pragma unroll
        for (int c = 0; c < 2; ++c) {
            bf16x8 av = *(const bf16x8*)&y2lds[m16][c * 32 + quad * 8];
            bf16x8 bv = *(const bf16x8*)(P.d3Wb + (size_t)(c0 + m16) * 64 + c * 32 + quad * 8);
            acc = __builtin_amdgcn_mfma_f32_16x16x32_bf16(av, bv, acc, 0, 0, 0);
        }
        const int col = c0 + m16;
        const float b = P.d3b[col];
        #pragma unroll
        for (int i = 0; i < 4; ++i) {
            const int n = n0 + quad * 4 + i;
            if (ti < P.limitv[n]) {
                int tr = ti + P.startv[n]; if (tr >= TT) tr -= TT;
                float v = P.s_next[(size_t)n * TT * SS + (size_t)tr * SS + col];
                lsum += fabsf(v - (acc[i] + b));
            }
        }
    }
    for (int off = 32; off >= 1; off >>= 1) lsum += __shfl_down(lsum, off);
    if (lane == 0) lred[w] = lsum;
    __syncthreads();
    if (tid == 0) atomicAdd(P.loss, lred[0] + lred[1] + lred[2] + lred[3]);
}

// ---------------------------------------------------------------- the persistent kernel
__global__ __launch_bounds__(256, 2)
void persist(PParams P)
{
    __shared__ __align__(16) unsigned short hstage[32 * HRS];   // 66176 B
    __shared__ __align__(16) char shu[8192];                    // red OR head ylds/y2lds/lred
    __shared__ int mint, sME, sML, sLoc;
    f32x4 (&red)[2][4][64] = *(f32x4 (*)[2][4][64])(shu);
    const int bid = blockIdx.x, tid = threadIdx.x;
    const int g = bid & 3, lbid = bid >> 2;     // group g on XCDs {g, g+4}
    const int half = lbid & 1;                  // subgroup = (g, half): one XCD
    const int ng0 = g * 32;
    // jb remap: even lbid -> cols 0-511, odd lbid -> cols 512-1023 (16 jcols/block)
    const int jb = ((lbid & 1) << 9) | ((lbid >> 1) << 4);

    // roster: publish my physical XCC into my subgroup's mask (verdict read post-barrier)
    if (tid == 0) {
        int xcc = __builtin_amdgcn_s_getreg(6164) & 15;   // hwreg(HW_REG_XCC_ID=20, 0, 4)
        __hip_atomic_fetch_or(P.bar + 5632 + (g * 2 + half) * 32, 1 << xcc,
                              __ATOMIC_RELAXED, __HIP_MEMORY_SCOPE_AGENT);
    }

    // ================= phase 0: cast (plain stores), split detection, h0, adec
    {
        const long N0 = 3072L * 160, N1 = N0 + 3072L * 1024, N2 = N1 + 3072L * 32,
                   N3 = N2 + 3072L * 1024, N4 = N3 + 1048576L, N5 = N4 + 1048576L,
                   N6 = N5 + 128L * 100 * 160, N7 = N6 + 131072L, N8 = N7 + 8192L,
                   N9 = N8 + 8192L;
        for (long i = (long)bid * 256 + tid; i < N9; i += (long)NBLK * 256) {
            if (i < N0)      P.eWih_b[i]      = f2bf(P.eWih[i]);
            else if (i < N1) P.eWhh_b[i - N0] = f2bf(P.eWhh[i - N0]);
            else if (i < N2) P.dWih_b[i - N1] = f2bf(P.dWih[i - N1]);
            else if (i < N3) P.dWhh_b[i - N2] = f2bf(P.dWhh[i - N2]);
            else if (i < N4) P.mlW_b[i - N3]  = f2bf(P.muW[i - N3]);
            else if (i < N5) P.mlW_b[1048576L + (i - N4)] = f2bf(P.lvW[i - N4]);
            else if (i < N6) {
                long j = i - N5;                  // n*16000 + t*160 + k
                int  k = (int)(j % 160);
                long nt = j / 160;
                int  t = (int)(nt % 100), n = (int)(nt / 100);
                float v = (k < SS) ? P.s[(size_t)n * TT * SS + (size_t)t * SS + k]
                                   : P.a[(size_t)n * TT * AA + (size_t)t * AA + (k - SS)];
                P.xenc_b[j] = f2bf(v);
            }
            else if (i < N7) P.d1Wb[i - N6] = f2bf(P.d1W[i - N6]);
            else if (i < N8) P.d2Wb[i - N7] = f2bf(P.d2W[i - N7]);
            else             P.d3Wb[i - N8] = f2bf(P.d3W[i - N8]);
        }
    }
    if (bid < NN_) {
        const int n = bid;
        if (tid == 0) mint = TT - 1;
        __syncthreads();
        int t = tid + 1;
        if (t < TT && tid < 128) {
            const float* row = P.s + (size_t)n * TT * SS + (size_t)t * SS;
            bool allz = true;
            for (int i = 0; i < SS; ++i) { if (row[i] != 0.0f) { allz = false; break; } }
            if (allz) atomicMin(&mint, t);
        }
        __syncthreads();
        const int m = mint, st = m + 1;
        if (tid == 0) { P.endv[n] = m - 1; P.startv[n] = st; P.limitv[n] = TT - 1 - m; }
        for (int idx = tid; idx < LL; idx += 256)
            P.hencAb[(size_t)n * LL + idx] = 0x3F80;   // bf16 1.0
        for (int idx = tid; idx < 50 * AA; idx += 256) {
            int i = idx >> 5, k = idx & 31;
            int tr = i + st; if (tr >= TT) tr -= TT;
            P.adec_b[(size_t)n * (50 * AA) + idx] =
                f2bf(P.a[(size_t)n * TT * AA + (size_t)tr * AA + k]);
        }
    }
    // one-time global heavy barrier: flush phase-0 plain stores, drop stale lines
    __syncthreads();
    if (tid == 0) __threadfence();
    gbar_global(P.bar, bid, tid, 1);
    if (tid == 0) __threadfence();
    __syncthreads();

    // ================= group-local ME/ML + locality verdict
    int ME, ML; bool myLoc;
    {
        int lv = 0, ev = 0;
        if (tid < 32) { lv = P.limitv[ng0 + tid]; ev = P.endv[ng0 + tid]; }
        if (tid < 64) {
            for (int off = 16; off >= 1; off >>= 1) {
                lv = max(lv, __shfl_down(lv, off));
                ev = max(ev, __shfl_down(ev, off));
            }
            if (tid == 0) { sML = lv; sME = ev; }
        }
        if (tid == 0) {
            int mk = __hip_atomic_load(P.bar + 5632 + (g * 2 + half) * 32,
                                       __ATOMIC_RELAXED, __HIP_MEMORY_SCOPE_AGENT);
            sLoc = (__popc((unsigned)mk) == 1) ? 1 : 0;   // subgroup on ONE XCD?
        }
        __syncthreads();
        ML = sML; ME = sME; myLoc = (sLoc != 0);
        __syncthreads();
    }
    // this wave's stage columns are produced on my XCD iff wave parity == lbid parity
    const bool wloc = myLoc && (((tid >> 6) & 1) == half);

    f32x4 hold = { 1.0f, 1.0f, 1.0f, 1.0f };   // enc h0 = ones (fp32 state lives here)
    int ggen = 0;

    // ================= encoder: t = 0..ME_g
    for (int t = 0; t <= ME; ++t) {
        if (lbid < 64) {
            const unsigned short* hib = (t & 1) ? P.hencBb : P.hencAb;
            unsigned short*       hob = (t & 1) ? P.hencAb : P.hencBb;
            gru_tile<160, false>(ng0, jb, tid, wloc, hib, hob,
                                 P.eWhh_b, P.eWih_b, P.xenc_b, P.ebih, P.ebhh,
                                 P.endv, P.hf_bf, t, red, hstage, hold);
        }
        gbar2(P.bar, g, half, lbid, myLoc, tid, ++ggen);
    }

    // ================= reparametrize (deposits decoder h0 into hold regs)
    if (lbid < 64) emb_tile(P, ng0, jb, tid, wloc, red, hstage, hold);
    gbar2(P.bar, g, half, lbid, myLoc, tid, ++ggen);

    // ================= decoder: i = 0..ML_g; matmul (i<ML) overlaps head for step i-1
    for (int i = 0; i <= ML; ++i) {
        const unsigned short* hib = (i & 1) ? P.hdecBb : P.hdecAb;
        if (lbid < 64) {
            if (i < ML) {
                unsigned short* hob = (i & 1) ? P.hdecAb : P.hdecBb;
                gru_tile<32, true>(ng0, jb, tid, wloc, hib, hob,
                                   P.dWhh_b, P.dWih_b, P.adec_b, P.dbih, P.dbhh,
                                   nullptr, nullptr, i, red, hstage, hold);
            }
        } else if (i >= 1) {
            head_tile(P, ng0 + (lbid - 64) * 16, tid, wloc, hib, i - 1, hstage, shu);
        }
        gbar2(P.bar, g, half, lbid, myLoc, tid, ++ggen);
    }
}

// ---------------------------------------------------------------- launch
extern "C" void kernel_launch(void* const* d_in, const int* in_sizes, int n_in,
                              void* d_out, int out_size, void* d_ws, size_t ws_size,
                              hipStream_t stream) {
    PParams P;
    P.s      = (const float*)d_in[0];
    P.a      = (const float*)d_in[1];
    P.s_next = (const float*)d_in[3];
    P.eps    = (const float*)d_in[4];
    P.eWih   = (const float*)d_in[5];
    P.eWhh   = (const float*)d_in[6];
    P.ebih   = (const float*)d_in[7];
    P.ebhh   = (const float*)d_in[8];
    P.muW    = (const float*)d_in[9];
    P.mub    = (const float*)d_in[10];
    P.lvW    = (const float*)d_in[11];
    P.lvb    = (const float*)d_in[12];
    // st1..st3 (13..18) dead code w.r.t. the loss
    P.dWih   = (const float*)d_in[19];
    P.dWhh   = (const float*)d_in[20];
    P.dbih   = (const float*)d_in[21];
    P.dbhh   = (const float*)d_in[22];
    P.d1W    = (const float*)d_in[23];
    P.d1b    = (const float*)d_in[24];
    P.d2W    = (const float*)d_in[25];
    P.d2b    = (const float*)d_in[26];
    P.d3W    = (const float*)d_in[27];
    P.d3b    = (const float*)d_in[28];
    P.loss   = (float*)d_out;

    char* p = (char*)d_ws;
    P.bar    = (int*)p;                    p += 24576;   // 6144 ints (barrier + roster)
    P.endv   = (int*)p;                    p += 512;
    P.startv = (int*)p;                    p += 512;
    P.limitv = (int*)p;                    p += 512;
    p += 2560;                             // pad
    P.hencAb = (unsigned short*)p;         p += 128 * 1024 * 2;
    P.hencBb = (unsigned short*)p;         p += 128 * 1024 * 2;
    P.hdecAb = (unsigned short*)p;         p += 128 * 1024 * 2;
    P.hdecBb = (unsigned short*)p;         p += 128 * 1024 * 2;
    P.hf_bf  = (unsigned short*)p;         p += 128 * 1024 * 2;
    P.eWih_b = (unsigned short*)p;         p += 3072 * 160 * 2;
    P.eWhh_b = (unsigned short*)p;         p += 3072 * 1024 * 2;
    P.dWih_b = (unsigned short*)p;         p += 3072 * 32 * 2;
    P.dWhh_b = (unsigned short*)p;         p += 3072 * 1024 * 2;
    P.mlW_b  = (unsigned short*)p;         p += 2048 * 1024 * 2;
    P.xenc_b = (unsigned short*)p;         p += 128 * 100 * 160 * 2;
    P.adec_b = (unsigned short*)p;         p += 128 * 50 * 32 * 2;
    P.d1Wb   = (unsigned short*)p;         p += 128 * 1024 * 2;
    P.d2Wb   = (unsigned short*)p;         p += 64 * 128 * 2;
    P.d3Wb   = (unsigned short*)p;         p += 128 * 64 * 2;

    hipLaunchKernelGGL(init_kernel, dim3(1), dim3(256), 0, stream, P.bar, P.loss);
    hipLaunchKernelGGL(persist, dim3(NBLK), dim3(256), 0, stream, P);
}

// Round 2
// 2707.992 us; speedup vs baseline: 693.9008x; 693.9008x over previous
//
#include <hip/hip_runtime.h>
#include <math.h>

#define NN_ 128   // batch
#define TT  100   // time steps
#define SS  128   // state dim
#define AA  32    // action dim
#define LL  1024  // hidden (= Z)
#define NBLK 260  // 4 groups x 65: 64 matmul blocks + 1 head/leader block per group
#define HRS  1034 // LDS h-stage row stride (bf16): max 2-way bank aliasing (free)

// Round-2 sync design: ONLY proven-coherent op classes on any cross-block path:
//   - __hip_atomic_* with __HIP_MEMORY_SCOPE_AGENT (flags, counters)
//   - asm global ops with "sc0 sc1" (system scope >= agent) for bulk data
// Barrier per group: 64 members store gen into private slot dwords (no RMW
// contention); single leader (head block) batch-polls the 256B slot region and
// stores one release flag; members poll release. No cross-XCD handshake.
// Length-sorted sample->group permutation cuts per-group step count ~22%.

typedef __attribute__((ext_vector_type(8))) short bf16x8;   // 8 bf16 in 4 VGPRs
typedef __attribute__((ext_vector_type(4))) float f32x4;
typedef __attribute__((ext_vector_type(4))) int   i32x4;

__device__ __forceinline__ float sigmoidf_(float x) { return 1.0f / (1.0f + expf(-x)); }
__device__ __forceinline__ unsigned short f2bf(float x) {
    union { float f; unsigned u; } v; v.f = x;
    return (unsigned short)((v.u + 0x7fffu + ((v.u >> 16) & 1u)) >> 16);   // RNE
}

// ---- coherent access helpers (system scope: sc0 sc1) -----------------------
__device__ __forceinline__ i32x4 ldg16(const unsigned short* p) {
    i32x4 r; asm volatile("global_load_dwordx4 %0, %1, off sc0 sc1"
                          : "=&v"(r) : "v"((unsigned long long)p));
    return r;   // caller must s_waitcnt vmcnt(0) before use
}
__device__ __forceinline__ void stg16(unsigned short* p, bf16x8 v) {
    union { bf16x8 h; i32x4 i; } u; u.h = v;
    asm volatile("global_store_dwordx4 %0, %1, off sc0 sc1"
                 :: "v"((unsigned long long)p), "v"(u.i) : "memory");
}
__device__ __forceinline__ void st2(unsigned short* p, unsigned short v) {
    asm volatile("global_store_short %0, %1, off sc0 sc1"
                 :: "v"((unsigned long long)p), "v"((unsigned)v) : "memory");
}
__device__ __forceinline__ int aload(const int* p) {
    return __hip_atomic_load(p, __ATOMIC_RELAXED, __HIP_MEMORY_SCOPE_AGENT);
}
__device__ __forceinline__ void astore(int* p, int v) {
    __hip_atomic_store(p, v, __ATOMIC_RELAXED, __HIP_MEMORY_SCOPE_AGENT);
}

struct PParams {
    const float *s, *a, *s_next, *eps;
    const float *eWih, *eWhh, *ebih, *ebhh;
    const float *muW, *mub, *lvW, *lvb;
    const float *dWih, *dWhh, *dbih, *dbhh;
    const float *d1W, *d1b, *d2W, *d2b, *d3W, *d3b;
    int *bar;
    int *endv, *startv, *limitv;
    unsigned short *hencAb, *hencBb, *hdecAb, *hdecBb, *hf_bf;
    unsigned short *eWih_b, *eWhh_b, *dWih_b, *dWhh_b, *mlW_b, *xenc_b, *adec_b;
    unsigned short *d1Wb, *d2Wb, *d3Wb;
    float *loss;
};

// ---------------------------------------------------------------- h-tile stage
// 32 rows (permuted) x 1024 cols bf16 (64 KB): 16 x 16B loads per thread.
__device__ __forceinline__ void stage_h32p(const unsigned short* __restrict__ src,
                                           const int* __restrict__ sperm,
                                           unsigned short* hstage, int tid) {
    i32x4 v[16];
    const int p = tid >> 7, col = (tid & 127) * 8;
    #pragma unroll
    for (int k = 0; k < 16; ++k) {
        const int row = sperm[p + 2 * k];           // physical sample id
        v[k] = ldg16(src + (size_t)row * LL + col);
    }
    asm volatile("s_waitcnt vmcnt(0)" ::: "memory");
    #pragma unroll
    for (int k = 0; k < 16; ++k)
        *(i32x4*)&hstage[(p + 2 * k) * HRS + col] = v[k];
}

// ---------------------------------------------------------------- barriers
// Global (phase 0 only): bar[g8*16] class counters; [128] master; [132] broken;
// [144+b*16] flags. Class sizes: bid%8<4 -> 33 blocks, else 32.
__device__ void gbar_global(int* bar, int bid, int tid, int gen) {
    __syncthreads();
    if (tid == 0) {
        if (aload(bar + 132) == 0) {
            const int g8 = bid & 7;
            const int tgt = (g8 < 4) ? 33 : 32;
            int pos = __hip_atomic_fetch_add(bar + g8 * 16, 1, __ATOMIC_RELAXED, __HIP_MEMORY_SCOPE_AGENT);
            if (pos + 1 == tgt * gen) {
                int mp = __hip_atomic_fetch_add(bar + 128, 1, __ATOMIC_RELAXED, __HIP_MEMORY_SCOPE_AGENT);
                if (mp + 1 == 8 * gen) {
                    for (int b = 0; b < NBLK; ++b)
                        astore(bar + 144 + b * 16, gen);
                }
            }
            int it = 0;
            while (aload(bar + 144 + bid * 16) < gen) {
                __builtin_amdgcn_s_sleep(1);
                if (++it > 4000000) { astore(bar + 132, 1); break; }
            }
        }
    }
    __syncthreads();
}

// Per-step group barrier. bar layout: 4608 + g*128 : [0..63] slots, [64] release.
// brk = bar[132]. sbrk = LDS-cached broken flag (skip all waits once set).
__device__ void gbar2(int* bar, int g, int lbid, int tid, int gen, int* sbrk) {
    asm volatile("s_waitcnt vmcnt(0)" ::: "memory");   // drain this wave's h stores
    __syncthreads();
    if (tid == 0 && *sbrk == 0) {
        int* sg  = bar + 4608 + g * 128;
        int* rel = sg + 64;
        int* brk = bar + 132;
        if (lbid == 64) {
            // ---- leader: wait all 64 slots >= gen (batched 256B system-scope read)
            const unsigned long long sga = (unsigned long long)sg;
            int it = 0;
            for (;;) {
                i32x4 a0, a1, a2, a3, a4, a5, a6, a7, a8, a9, a10, a11, a12, a13, a14, a15;
                asm volatile(
                    "global_load_dwordx4 %0, %16, off sc0 sc1\n\t"
                    "global_load_dwordx4 %1, %16, off offset:16 sc0 sc1\n\t"
                    "global_load_dwordx4 %2, %16, off offset:32 sc0 sc1\n\t"
                    "global_load_dwordx4 %3, %16, off offset:48 sc0 sc1\n\t"
                    "global_load_dwordx4 %4, %16, off offset:64 sc0 sc1\n\t"
                    "global_load_dwordx4 %5, %16, off offset:80 sc0 sc1\n\t"
                    "global_load_dwordx4 %6, %16, off offset:96 sc0 sc1\n\t"
                    "global_load_dwordx4 %7, %16, off offset:112 sc0 sc1\n\t"
                    "global_load_dwordx4 %8, %16, off offset:128 sc0 sc1\n\t"
                    "global_load_dwordx4 %9, %16, off offset:144 sc0 sc1\n\t"
                    "global_load_dwordx4 %10, %16, off offset:160 sc0 sc1\n\t"
                    "global_load_dwordx4 %11, %16, off offset:176 sc0 sc1\n\t"
                    "global_load_dwordx4 %12, %16, off offset:192 sc0 sc1\n\t"
                    "global_load_dwordx4 %13, %16, off offset:208 sc0 sc1\n\t"
                    "global_load_dwordx4 %14, %16, off offset:224 sc0 sc1\n\t"
                    "global_load_dwordx4 %15, %16, off offset:240 sc0 sc1\n\t"
                    "s_waitcnt vmcnt(0)"
                    : "=&v"(a0), "=&v"(a1), "=&v"(a2), "=&v"(a3),
                      "=&v"(a4), "=&v"(a5), "=&v"(a6), "=&v"(a7),
                      "=&v"(a8), "=&v"(a9), "=&v"(a10), "=&v"(a11),
                      "=&v"(a12), "=&v"(a13), "=&v"(a14), "=&v"(a15)
                    : "v"(sga) : "memory");
                int mn = a0[0];
                #define MN4(x) mn = min(mn, min(min((x)[0], (x)[1]), min((x)[2], (x)[3])))
                MN4(a0); MN4(a1); MN4(a2); MN4(a3); MN4(a4); MN4(a5); MN4(a6); MN4(a7);
                MN4(a8); MN4(a9); MN4(a10); MN4(a11); MN4(a12); MN4(a13); MN4(a14); MN4(a15);
                #undef MN4
                if (mn >= gen) break;
                __builtin_amdgcn_s_sleep(1);
                if (((++it) & 2047) == 0) {
                    if (aload(brk)) { *sbrk = 1; break; }
                    if (it > 2000000) { astore(brk, 1); *sbrk = 1; break; }
                }
            }
            astore(rel, gen);
        } else {
            astore(sg + lbid, gen);                    // arrive (no RMW contention)
            int it = 0;
            while (aload(rel) < gen) {
                __builtin_amdgcn_s_sleep(1);
                if (((++it) & 2047) == 0) {
                    if (aload(brk)) { *sbrk = 1; break; }
                    if (it > 2000000) { astore(brk, 1); *sbrk = 1; break; }
                }
            }
        }
    }
    __syncthreads();
}

// ---------------------------------------------------------------- init (separate launch)
__global__ void init_kernel(int* bar, float* loss) {
    for (int i = threadIdx.x; i < 6144; i += 256) bar[i] = 0;
    if (threadIdx.x == 0) loss[0] = 0.0f;
}

// ---------------------------------------------------------------- GRU step matmul tile
// Per group: 64 blocks x 16 j-cols (3 gates), 32 samples (permuted via sperm).
// Waves: nh=w&1 sample-half, kh=w>>1 K-half. fp32 h state lives in `hold` regs
// of kh==0 waves; h stores coalesced 16B system-scope via LDS transpose.
template<int XK, bool IS_DEC>
__device__ void gru_tile(const int* __restrict__ sperm, const int jb, const int tid,
    const unsigned short* __restrict__ h_bf, unsigned short* __restrict__ ho_bf,
    const unsigned short* __restrict__ Whh_b, const unsigned short* __restrict__ Wih_b,
    const unsigned short* __restrict__ x_bf,
    const float* __restrict__ bih, const float* __restrict__ bhh,
    const int* __restrict__ endv, unsigned short* __restrict__ hf_bf,
    int t, f32x4 (&red)[2][4][64], unsigned short* hstage, f32x4& hold)
{
    const int lane = tid & 63, w = tid >> 6;
    const int nh = w & 1, kh = w >> 1;
    const int m = lane & 15, quad = lane >> 4;
    const int jcol = jb + m;

    stage_h32p(h_bf, sperm, hstage, tid);
    __syncthreads();

    f32x4 accr{}, accz{}, acchn{}, accxn{};

    {   // hidden: K = 1024, 32 chunks, split 16/16 across kh; A from LDS
        const int arow = (nh * 16 + m) * HRS + quad * 8;
        const unsigned short* brp = Whh_b + (size_t)(0 * LL + jcol) * LL + quad * 8;
        const unsigned short* bzp = Whh_b + (size_t)(1 * LL + jcol) * LL + quad * 8;
        const unsigned short* bnp = Whh_b + (size_t)(2 * LL + jcol) * LL + quad * 8;
        #pragma unroll 4
        for (int c = kh * 16; c < kh * 16 + 16; ++c) {
            const int k0 = c * 32;
            bf16x8 av = *(const bf16x8*)&hstage[arow + k0];
            bf16x8 br = *(const bf16x8*)(brp + k0);
            bf16x8 bz = *(const bf16x8*)(bzp + k0);
            bf16x8 bn = *(const bf16x8*)(bnp + k0);
            accr  = __builtin_amdgcn_mfma_f32_16x16x32_bf16(av, br, accr, 0, 0, 0);
            accz  = __builtin_amdgcn_mfma_f32_16x16x32_bf16(av, bz, accz, 0, 0, 0);
            acchn = __builtin_amdgcn_mfma_f32_16x16x32_bf16(av, bn, acchn, 0, 0, 0);
        }
    }
    {   // input: K = XK (enc 160, dec 32); read-only -> plain L1/L2-cached loads
        const int XC = XK / 32, XC0 = (XC + 1) / 2;
        const size_t xstride = IS_DEC ? (size_t)(50 * AA) : (size_t)(TT * (SS + AA));
        const int nphys = sperm[nh * 16 + m];
        const unsigned short* xp  = x_bf + (size_t)nphys * xstride + (size_t)t * XK + quad * 8;
        const unsigned short* brp = Wih_b + (size_t)(0 * LL + jcol) * XK + quad * 8;
        const unsigned short* bzp = Wih_b + (size_t)(1 * LL + jcol) * XK + quad * 8;
        const unsigned short* bnp = Wih_b + (size_t)(2 * LL + jcol) * XK + quad * 8;
        #pragma unroll
        for (int c = (kh ? XC0 : 0); c < (kh ? XC : XC0); ++c) {
            const int k0 = c * 32;
            bf16x8 av = *(const bf16x8*)(xp + k0);
            bf16x8 br = *(const bf16x8*)(brp + k0);
            bf16x8 bz = *(const bf16x8*)(bzp + k0);
            bf16x8 bn = *(const bf16x8*)(bnp + k0);
            accr  = __builtin_amdgcn_mfma_f32_16x16x32_bf16(av, br, accr, 0, 0, 0);
            accz  = __builtin_amdgcn_mfma_f32_16x16x32_bf16(av, bz, accz, 0, 0, 0);
            accxn = __builtin_amdgcn_mfma_f32_16x16x32_bf16(av, bn, accxn, 0, 0, 0);
        }
    }
    if (kh == 1) {
        red[nh][0][lane] = accr;  red[nh][1][lane] = accz;
        red[nh][2][lane] = acchn; red[nh][3][lane] = accxn;
    }
    __syncthreads();
    if (kh == 0) {
        accr  += red[nh][0][lane];  accz  += red[nh][1][lane];
        acchn += red[nh][2][lane];  accxn += red[nh][3][lane];
        const float br_  = bih[jcol] + bhh[jcol];
        const float bz_  = bih[LL + jcol] + bhh[LL + jcol];
        const float bxn_ = bih[2 * LL + jcol];
        const float bhn_ = bhh[2 * LL + jcol];
        unsigned short* tr = hstage + nh * (16 * 24);    // wave-private transpose scratch
        #pragma unroll
        for (int i = 0; i < 4; ++i) {
            const int n = sperm[nh * 16 + quad * 4 + i]; // C layout: row=quad*4+i, col=m
            float r = sigmoidf_(accr[i] + br_);
            float z = sigmoidf_(accz[i] + bz_);
            float g = tanhf(accxn[i] + bxn_ + r * (acchn[i] + bhn_));
            float hn = (1.0f - z) * g + z * hold[i];
            hold[i] = hn;
            unsigned short hb = f2bf(hn);
            tr[(quad * 4 + i) * 24 + m] = hb;            // LDS transpose (wave-lockstep)
            if (!IS_DEC) { if (endv[n] == t) st2(hf_bf + (size_t)n * LL + jcol, hb); }
        }
        // coalesced 16B n-major stores: lanes 0..31 each store 8 bf16
        if (lane < 32) {
            const int nl = lane >> 1, jh = lane & 1;
            bf16x8 vv = *(const bf16x8*)&tr[nl * 24 + jh * 8];
            stg16(ho_bf + (size_t)sperm[nh * 16 + nl] * LL + jb + jh * 8, vv);
        }
    }
}

// ---------------------------------------------------------------- reparametrize tile
__device__ void emb_tile(const PParams& P, const int* __restrict__ sperm, const int jb,
                         const int tid, f32x4 (&red)[2][4][64], unsigned short* hstage,
                         f32x4& hold)
{
    const int lane = tid & 63, w = tid >> 6;
    const int nh = w & 1, kh = w >> 1;
    const int m = lane & 15, quad = lane >> 4;
    const int jcol = jb + m;

    stage_h32p(P.hf_bf, sperm, hstage, tid);
    __syncthreads();

    f32x4 accm{}, accl{};
    const int arow = (nh * 16 + m) * HRS + quad * 8;
    const unsigned short* bmp = P.mlW_b + (size_t)jcol * LL + quad * 8;
    const unsigned short* blp = P.mlW_b + (size_t)(LL + jcol) * LL + quad * 8;
    #pragma unroll 4
    for (int c = kh * 16; c < kh * 16 + 16; ++c) {
        const int k0 = c * 32;
        bf16x8 av = *(const bf16x8*)&hstage[arow + k0];
        bf16x8 bm = *(const bf16x8*)(bmp + k0);
        bf16x8 bl = *(const bf16x8*)(blp + k0);
        accm = __builtin_amdgcn_mfma_f32_16x16x32_bf16(av, bm, accm, 0, 0, 0);
        accl = __builtin_amdgcn_mfma_f32_16x16x32_bf16(av, bl, accl, 0, 0, 0);
    }
    if (kh == 1) { red[nh][0][lane] = accm; red[nh][1][lane] = accl; }
    __syncthreads();
    if (kh == 0) {
        accm += red[nh][0][lane]; accl += red[nh][1][lane];
        unsigned short* tr = hstage + nh * (16 * 24);
        #pragma unroll
        for (int i = 0; i < 4; ++i) {
            const int n = sperm[nh * 16 + quad * 4 + i];
            float mu = accm[i] + P.mub[jcol];
            float lv = accl[i] + P.lvb[jcol];
            float e = mu + expf(0.5f * lv) * P.eps[(size_t)n * LL + jcol];
            hold[i] = e;
            tr[(quad * 4 + i) * 24 + m] = f2bf(e);
        }
        if (lane < 32) {
            const int nl = lane >> 1, jh = lane & 1;
            bf16x8 vv = *(const bf16x8*)&tr[nl * 24 + jh * 8];
            stg16(P.hdecAb + (size_t)sperm[nh * 16 + nl] * LL + jb + jh * 8, vv);
        }
    }
}

// ---------------------------------------------------------------- MFMA decoder head
// One block per group handles all 32 (permuted) samples.
__device__ void head_tile(const PParams& P, const int* __restrict__ sperm, const int tid,
                          const unsigned short* __restrict__ h_bf, int ti,
                          unsigned short* hstage, char* shu)
{
    auto& ylds  = *(unsigned short (*)[32][136])(shu);           // 8704 B
    auto& y2lds = *(unsigned short (*)[32][72])(shu + 8704);     // 4608 B
    float* lred = (float*)(shu + 8704 + 4608);
    const int lane = tid & 63, w = tid >> 6;
    const int m16 = lane & 15, quad = lane >> 4;

    stage_h32p(h_bf, sperm, hstage, tid);
    __syncthreads();

    // ---- y1: [32][128], 16 tiles (r=t&1, c=t>>1), wave w -> t = w*4 + jt
    #pragma unroll
    for (int jt = 0; jt < 4; ++jt) {
        const int t_ = w * 4 + jt, r = t_ & 1, c = t_ >> 1;
        f32x4 acc{};
        const int abase = (r * 16 + m16) * HRS + quad * 8;
        const unsigned short* bp = P.d1Wb + (size_t)(c * 16 + m16) * LL + quad * 8;
        #pragma unroll 4
        for (int ch = 0; ch < 32; ++ch) {
            bf16x8 av = *(const bf16x8*)&hstage[abase + ch * 32];
            bf16x8 bv = *(const bf16x8*)(bp + ch * 32);
            acc = __builtin_amdgcn_mfma_f32_16x16x32_bf16(av, bv, acc, 0, 0, 0);
        }
        const float b = P.d1b[c * 16 + m16];
        #pragma unroll
        for (int i = 0; i < 4; ++i)
            ylds[r * 16 + quad * 4 + i][c * 16 + m16] = f2bf(fmaxf(acc[i] + b, 0.0f));
    }
    __syncthreads();

    // ---- y2: [32][64], 8 tiles, wave w -> t = w*2 + jt
    #pragma unroll
    for (int jt = 0; jt < 2; ++jt) {
        const int t_ = w * 2 + jt, r = t_ & 1, c = t_ >> 1;
        f32x4 acc{};
        #pragma unroll
        for (int ch = 0; ch < 4; ++ch) {
            bf16x8 av = *(const bf16x8*)&ylds[r * 16 + m16][ch * 32 + quad * 8];
            bf16x8 bv = *(const bf16x8*)(P.d2Wb + (size_t)(c * 16 + m16) * 128 + ch * 32 + quad * 8);
            acc = __builtin_amdgcn_mfma_f32_16x16x32_bf16(av, bv, acc, 0, 0, 0);
        }
        const float b = P.d2b[c * 16 + m16];
        #pragma unroll
        for (int i = 0; i < 4; ++i)
            y2lds[r * 16 + quad * 4 + i][c * 16 + m16] = f2bf(fmaxf(acc[i] + b, 0.0f));
    }
    __syncthreads();

    // ---- y3 + fused masked L1: 16 tiles, wave w -> t = w*4 + jt
    float lsum = 0.0f;
    #pragma unroll
    for (int jt = 0; jt < 4; ++jt) {
        const int t_ = w * 4 + jt, r = t_ & 1, c = t_ >> 1;
        f32x4 acc{};
        #pragma unroll
        for (int ch = 0; ch < 2; ++ch) {
            bf16x8 av = *(const bf16x8*)&y2lds[r * 16 + m16][ch * 32 + quad * 8];
            bf16x8 bv = *(const bf16x8*)(P.d3Wb + (size_t)(c * 16 + m16) * 64 + ch * 32 + quad * 8);
            acc = __builtin_amdgcn_mfma_f32_16x16x32_bf16(av, bv, acc, 0, 0, 0);
        }
        const int col = c * 16 + m16;
        const float b = P.d3b[col];
        #pragma unroll
        for (int i = 0; i < 4; ++i) {
            const int n = sperm[r * 16 + quad * 4 + i];
            if (ti < P.limitv[n]) {
                int trw = ti + P.startv[n]; if (trw >= TT) trw -= TT;
                float v = P.s_next[(size_t)n * TT * SS + (size_t)trw * SS + col];
                lsum += fabsf(v - (acc[i] + b));
            }
        }
    }
    for (int off = 32; off >= 1; off >>= 1) lsum += __shfl_down(lsum, off);
    if (lane == 0) lred[w] = lsum;
    __syncthreads();
    if (tid == 0) atomicAdd(P.loss, lred[0] + lred[1] + lred[2] + lred[3]);
}

// ---------------------------------------------------------------- the persistent kernel
__global__ __launch_bounds__(256, 2)
void persist(PParams P)
{
    __shared__ __align__(16) unsigned short hstage[32 * HRS];   // 66176 B
    __shared__ __align__(16) char shu[13568];                   // red OR head ylds/y2lds/lred
    __shared__ int sperm[32];                                   // group's permuted sample ids
    __shared__ int mint, sME, sML, sbrk;
    f32x4 (&red)[2][4][64] = *(f32x4 (*)[2][4][64])(shu);
    const int bid = blockIdx.x, tid = threadIdx.x;
    const int g = bid & 3, lbid = bid >> 2;    // group g; lbid 0..63 matmul, 64 head/leader
    const int jb = lbid * 16;                  // matmul blocks only (lbid < 64)

    // ================= phase 0: cast (plain stores), split detection, h0, adec
    {
        const long N0 = 3072L * 160, N1 = N0 + 3072L * 1024, N2 = N1 + 3072L * 32,
                   N3 = N2 + 3072L * 1024, N4 = N3 + 1048576L, N5 = N4 + 1048576L,
                   N6 = N5 + 128L * 100 * 160, N7 = N6 + 131072L, N8 = N7 + 8192L,
                   N9 = N8 + 8192L;
        for (long i = (long)bid * 256 + tid; i < N9; i += (long)NBLK * 256) {
            if (i < N0)      P.eWih_b[i]      = f2bf(P.eWih[i]);
            else if (i < N1) P.eWhh_b[i - N0] = f2bf(P.eWhh[i - N0]);
            else if (i < N2) P.dWih_b[i - N1] = f2bf(P.dWih[i - N1]);
            else if (i < N3) P.dWhh_b[i - N2] = f2bf(P.dWhh[i - N2]);
            else if (i < N4) P.mlW_b[i - N3]  = f2bf(P.muW[i - N3]);
            else if (i < N5) P.mlW_b[1048576L + (i - N4)] = f2bf(P.lvW[i - N4]);
            else if (i < N6) {
                long j = i - N5;                  // n*16000 + t*160 + k
                int  k = (int)(j % 160);
                long nt = j / 160;
                int  t = (int)(nt % 100), n = (int)(nt / 100);
                float v = (k < SS) ? P.s[(size_t)n * TT * SS + (size_t)t * SS + k]
                                   : P.a[(size_t)n * TT * AA + (size_t)t * AA + (k - SS)];
                P.xenc_b[j] = f2bf(v);
            }
            else if (i < N7) P.d1Wb[i - N6] = f2bf(P.d1W[i - N6]);
            else if (i < N8) P.d2Wb[i - N7] = f2bf(P.d2W[i - N7]);
            else             P.d3Wb[i - N8] = f2bf(P.d3W[i - N8]);
        }
    }
    if (bid < NN_) {
        const int n = bid;
        if (tid == 0) mint = TT - 1;
        __syncthreads();
        int t = tid + 1;
        if (t < TT && tid < 128) {
            const float* row = P.s + (size_t)n * TT * SS + (size_t)t * SS;
            bool allz = true;
            for (int i = 0; i < SS; ++i) { if (row[i] != 0.0f) { allz = false; break; } }
            if (allz) atomicMin(&mint, t);
        }
        __syncthreads();
        const int m = mint, st = m + 1;
        if (tid == 0) { P.endv[n] = m - 1; P.startv[n] = st; P.limitv[n] = TT - 1 - m; }
        for (int idx = tid; idx < LL; idx += 256)
            P.hencAb[(size_t)n * LL + idx] = 0x3F80;   // bf16 1.0
        for (int idx = tid; idx < 50 * AA; idx += 256) {
            int i = idx >> 5, k = idx & 31;
            int tr = i + st; if (tr >= TT) tr -= TT;
            P.adec_b[(size_t)n * (50 * AA) + idx] =
                f2bf(P.a[(size_t)n * TT * AA + (size_t)tr * AA + k]);
        }
    }
    // one-time global heavy barrier: flush phase-0 plain stores, drop stale lines
    __syncthreads();
    if (tid == 0) __threadfence();
    gbar_global(P.bar, bid, tid, 1);
    if (tid == 0) __threadfence();
    __syncthreads();

    // ================= length-sorted permutation (identical in every block)
    {
        int* keys = (int*)shu;
        if (tid < 128) keys[tid] = P.endv[tid];
        if (tid == 0) sbrk = 0;
        __syncthreads();
        if (tid < 128) {
            const int k = keys[tid];
            int r = 0;
            for (int j = 0; j < 128; ++j) {
                const int kj = keys[j];
                r += (kj < k) | ((kj == k) & (j < tid));
            }
            if (r >= g * 32 && r < g * 32 + 32) sperm[r - g * 32] = tid;  // rank -> sample
        }
        __syncthreads();
    }

    // ================= group ME = max(end), ML = max(limit) over its 32 samples
    int ME, ML;
    {
        int lv = 0, ev = 0;
        if (tid < 32) { const int n = sperm[tid]; lv = P.limitv[n]; ev = P.endv[n]; }
        if (tid < 64) {
            for (int off = 16; off >= 1; off >>= 1) {
                lv = max(lv, __shfl_down(lv, off));
                ev = max(ev, __shfl_down(ev, off));
            }
            if (tid == 0) { sML = lv; sME = ev; }
        }
        __syncthreads();
        ML = sML; ME = sME;
        __syncthreads();
    }

    f32x4 hold = { 1.0f, 1.0f, 1.0f, 1.0f };   // enc h0 = ones (fp32 state lives here)
    int ggen = 0;

    // ================= encoder: t = 0..ME_g
    for (int t = 0; t <= ME; ++t) {
        if (lbid < 64) {
            const unsigned short* hib = (t & 1) ? P.hencBb : P.hencAb;
            unsigned short*       hob = (t & 1) ? P.hencAb : P.hencBb;
            gru_tile<160, false>(sperm, jb, tid, hib, hob,
                                 P.eWhh_b, P.eWih_b, P.xenc_b, P.ebih, P.ebhh,
                                 P.endv, P.hf_bf, t, red, hstage, hold);
        }
        gbar2(P.bar, g, lbid, tid, ++ggen, &sbrk);
    }

    // ================= reparametrize (deposits decoder h0 into hold regs)
    if (lbid < 64) emb_tile(P, sperm, jb, tid, red, hstage, hold);
    gbar2(P.bar, g, lbid, tid, ++ggen, &sbrk);

    // ================= decoder: i = 0..ML_g; matmul (i<ML) overlaps head for step i-1
    for (int i = 0; i <= ML; ++i) {
        const unsigned short* hib = (i & 1) ? P.hdecBb : P.hdecAb;
        if (lbid < 64) {
            if (i < ML) {
                unsigned short* hob = (i & 1) ? P.hdecAb : P.hdecBb;
                gru_tile<32, true>(sperm, jb, tid, hib, hob,
                                   P.dWhh_b, P.dWih_b, P.adec_b, P.dbih, P.dbhh,
                                   nullptr, nullptr, i, red, hstage, hold);
            }
        } else if (i >= 1) {
            head_tile(P, sperm, tid, hib, i - 1, hstage, shu);
        }
        gbar2(P.bar, g, lbid, tid, ++ggen, &sbrk);
    }
}

// ---------------------------------------------------------------- launch
extern "C" void kernel_launch(void* const* d_in, const int* in_sizes, int n_in,
                              void* d_out, int out_size, void* d_ws, size_t ws_size,
                              hipStream_t stream) {
    PParams P;
    P.s      = (const float*)d_in[0];
    P.a      = (const float*)d_in[1];
    P.s_next = (const float*)d_in[3];
    P.eps    = (const float*)d_in[4];
    P.eWih   = (const float*)d_in[5];
    P.eWhh   = (const float*)d_in[6];
    P.ebih   = (const float*)d_in[7];
    P.ebhh   = (const float*)d_in[8];
    P.muW    = (const float*)d_in[9];
    P.mub    = (const float*)d_in[10];
    P.lvW    = (const float*)d_in[11];
    P.lvb    = (const float*)d_in[12];
    // st1..st3 (13..18) dead code w.r.t. the loss
    P.dWih   = (const float*)d_in[19];
    P.dWhh   = (const float*)d_in[20];
    P.dbih   = (const float*)d_in[21];
    P.dbhh   = (const float*)d_in[22];
    P.d1W    = (const float*)d_in[23];
    P.d1b    = (const float*)d_in[24];
    P.d2W    = (const float*)d_in[25];
    P.d2b    = (const float*)d_in[26];
    P.d3W    = (const float*)d_in[27];
    P.d3b    = (const float*)d_in[28];
    P.loss   = (float*)d_out;

    char* p = (char*)d_ws;
    P.bar    = (int*)p;                    p += 24576;   // 6144 ints (barriers)
    P.endv   = (int*)p;                    p += 512;
    P.startv = (int*)p;                    p += 512;
    P.limitv = (int*)p;                    p += 512;
    p += 2560;                             // pad
    P.hencAb = (unsigned short*)p;         p += 128 * 1024 * 2;
    P.hencBb = (unsigned short*)p;         p += 128 * 1024 * 2;
    P.hdecAb = (unsigned short*)p;         p += 128 * 1024 * 2;
    P.hdecBb = (unsigned short*)p;         p += 128 * 1024 * 2;
    P.hf_bf  = (unsigned short*)p;         p += 128 * 1024 * 2;
    P.eWih_b = (unsigned short*)p;         p += 3072 * 160 * 2;
    P.eWhh_b = (unsigned short*)p;         p += 3072 * 1024 * 2;
    P.dWih_b = (unsigned short*)p;         p += 3072 * 32 * 2;
    P.dWhh_b = (unsigned short*)p;         p += 3072 * 1024 * 2;
    P.mlW_b  = (unsigned short*)p;         p += 2048 * 1024 * 2;
    P.xenc_b = (unsigned short*)p;         p += 128 * 100 * 160 * 2;
    P.adec_b = (unsigned short*)p;         p += 128 * 50 * 32 * 2;
    P.d1Wb   = (unsigned short*)p;         p += 128 * 1024 * 2;
    P.d2Wb   = (unsigned short*)p;         p += 64 * 128 * 2;
    P.d3Wb   = (unsigned short*)p;         p += 128 * 64 * 2;

    hipLaunchKernelGGL(init_kernel, dim3(1), dim3(256), 0, stream, P.bar, P.loss);
    hipLaunchKernelGGL(persist, dim3(NBLK), dim3(256), 0, stream, P);
}

// Round 3
// 2077.593 us; speedup vs baseline: 904.4496x; 1.3034x over previous
//
#include <hip/hip_runtime.h>
#include <math.h>

#define NN_ 128   // batch
#define TT  100   // time steps
#define SS  128   // state dim
#define AA  32    // action dim
#define LL  1024  // hidden (= Z)
#define NBLK 264  // 4 groups x 66; 64 matmul blocks + 2 head blocks per group
#define HRS  1034 // LDS h-stage row stride (bf16): max 2-way bank aliasing (free)

// Round-3: round-0's PROVEN symmetric barrier (4 sub-counter fetch-add tree,
// 16.2us/step measured) + round-2's PROVEN length-sorted sample->group
// permutation (steps 149 -> ~113). Only coherent op classes cross-block:
// __hip_atomic_* AGENT scope and asm global ops with "sc0 sc1".

typedef __attribute__((ext_vector_type(8))) short bf16x8;   // 8 bf16 in 4 VGPRs
typedef __attribute__((ext_vector_type(4))) float f32x4;
typedef __attribute__((ext_vector_type(4))) int   i32x4;

__device__ __forceinline__ float sigmoidf_(float x) { return 1.0f / (1.0f + expf(-x)); }
__device__ __forceinline__ unsigned short f2bf(float x) {
    union { float f; unsigned u; } v; v.f = x;
    return (unsigned short)((v.u + 0x7fffu + ((v.u >> 16) & 1u)) >> 16);   // RNE
}

// ---- coherent access helpers (system scope: sc0 sc1) -----------------------
__device__ __forceinline__ i32x4 ldg16(const unsigned short* p) {
    i32x4 r; asm volatile("global_load_dwordx4 %0, %1, off sc0 sc1"
                          : "=&v"(r) : "v"((unsigned long long)p));
    return r;   // caller must s_waitcnt vmcnt(0) before use
}
__device__ __forceinline__ void stg16(unsigned short* p, bf16x8 v) {
    union { bf16x8 h; i32x4 i; } u; u.h = v;
    asm volatile("global_store_dwordx4 %0, %1, off sc0 sc1"
                 :: "v"((unsigned long long)p), "v"(u.i) : "memory");
}
__device__ __forceinline__ void st2(unsigned short* p, unsigned short v) {
    asm volatile("global_store_short %0, %1, off sc0 sc1"
                 :: "v"((unsigned long long)p), "v"((unsigned)v) : "memory");
}
__device__ __forceinline__ int aload(const int* p) {
    return __hip_atomic_load(p, __ATOMIC_RELAXED, __HIP_MEMORY_SCOPE_AGENT);
}
__device__ __forceinline__ void astore(int* p, int v) {
    __hip_atomic_store(p, v, __ATOMIC_RELAXED, __HIP_MEMORY_SCOPE_AGENT);
}

struct PParams {
    const float *s, *a, *s_next, *eps;
    const float *eWih, *eWhh, *ebih, *ebhh;
    const float *muW, *mub, *lvW, *lvb;
    const float *dWih, *dWhh, *dbih, *dbhh;
    const float *d1W, *d1b, *d2W, *d2b, *d3W, *d3b;
    int *bar;
    int *endv, *startv, *limitv;
    unsigned short *hencAb, *hencBb, *hdecAb, *hdecBb, *hf_bf;
    unsigned short *eWih_b, *eWhh_b, *dWih_b, *dWhh_b, *mlW_b, *xenc_b, *adec_b;
    unsigned short *d1Wb, *d2Wb, *d3Wb;
    float *loss;
};

// ---------------------------------------------------------------- h-tile stages
// 32 rows (permuted) x 1024 cols bf16 (64 KB): 16 x 16B loads per thread.
__device__ __forceinline__ void stage_h32p(const unsigned short* __restrict__ src,
                                           const int* __restrict__ sperm,
                                           unsigned short* hstage, int tid) {
    i32x4 v[16];
    const int p = tid >> 7, col = (tid & 127) * 8;
    #pragma unroll
    for (int k = 0; k < 16; ++k) {
        const int row = sperm[p + 2 * k];           // physical sample id
        v[k] = ldg16(src + (size_t)row * LL + col);
    }
    asm volatile("s_waitcnt vmcnt(0)" ::: "memory");
    #pragma unroll
    for (int k = 0; k < 16; ++k)
        *(i32x4*)&hstage[(p + 2 * k) * HRS + col] = v[k];
}
// 16 rows (head blocks), sperm16 = rank base of this head block
__device__ __forceinline__ void stage_h16p(const unsigned short* __restrict__ src,
                                           const int* __restrict__ sperm16,
                                           unsigned short* hstage, int tid) {
    i32x4 v[8];
    const int p = tid >> 7, col = (tid & 127) * 8;
    #pragma unroll
    for (int k = 0; k < 8; ++k) {
        const int row = sperm16[p + 2 * k];
        v[k] = ldg16(src + (size_t)row * LL + col);
    }
    asm volatile("s_waitcnt vmcnt(0)" ::: "memory");
    #pragma unroll
    for (int k = 0; k < 8; ++k)
        *(i32x4*)&hstage[(p + 2 * k) * HRS + col] = v[k];
}

// ---------------------------------------------------------------- barriers
// Global (phase 0 only): bar[g8*16] 8 counters; [128] master; [132] broken;
// [144+b*16] flags. 264/8 = 33 per class.
__device__ void gbar_global(int* bar, int bid, int tid, int gen) {
    __syncthreads();
    if (tid == 0) {
        if (aload(bar + 132) == 0) {
            const int g8 = bid & 7;
            int pos = __hip_atomic_fetch_add(bar + g8 * 16, 1, __ATOMIC_RELAXED, __HIP_MEMORY_SCOPE_AGENT);
            if (pos + 1 == (NBLK / 8) * gen) {
                int mp = __hip_atomic_fetch_add(bar + 128, 1, __ATOMIC_RELAXED, __HIP_MEMORY_SCOPE_AGENT);
                if (mp + 1 == 8 * gen) {
                    for (int b = 0; b < NBLK; ++b)
                        astore(bar + 144 + b * 16, gen);
                }
            }
            int it = 0;
            while (aload(bar + 144 + bid * 16) < gen) {
                __builtin_amdgcn_s_sleep(1);
                if (++it > 4000000) { astore(bar + 132, 1); break; }
            }
        }
    }
    __syncthreads();
}

// Group-local per-step barrier (round-0 mechanics): gb[0,16,32,48] 4 sub-counters
// (17/17/16/16 of the 66 blocks); gb[64] master; gb[80] flag. Monotone gens.
// broken checked only every 2048 poll iterations; cached in LDS (sbrk).
__device__ void gbar_group(int* gb, int* brk, int lbid, int tid, int gen, int* sbrk) {
    asm volatile("s_waitcnt vmcnt(0)" ::: "memory");   // drain this wave's h stores
    __syncthreads();
    if (tid == 0) {
        const int s = lbid & 3;
        const int tgt = (s < 2) ? 17 : 16;   // 66 = 17+17+16+16
        int pos = __hip_atomic_fetch_add(gb + s * 16, 1, __ATOMIC_RELAXED, __HIP_MEMORY_SCOPE_AGENT);
        if (pos + 1 == tgt * gen) {
            int mp = __hip_atomic_fetch_add(gb + 64, 1, __ATOMIC_RELAXED, __HIP_MEMORY_SCOPE_AGENT);
            if (mp + 1 == 4 * gen)
                astore(gb + 80, gen);
        }
        if (*sbrk == 0) {
            int it = 0;
            while (aload(gb + 80) < gen) {
                __builtin_amdgcn_s_sleep(1);
                if (((++it) & 2047) == 0) {
                    if (aload(brk)) { *sbrk = 1; break; }
                    if (it > 2000000) { astore(brk, 1); *sbrk = 1; break; }
                }
            }
        }
    }
    __syncthreads();
}

// ---------------------------------------------------------------- init (separate launch)
__global__ void init_kernel(int* bar, float* loss) {
    for (int i = threadIdx.x; i < 5632; i += 256) bar[i] = 0;
    if (threadIdx.x == 0) loss[0] = 0.0f;
}

// ---------------------------------------------------------------- GRU step matmul tile
// Per group: 64 blocks x 16 j-cols (3 gates), 32 samples (permuted via sperm).
// Waves: nh=w&1 sample-half, kh=w>>1 K-half. fp32 h state lives in `hold` regs
// of kh==0 waves; h stores coalesced 16B system-scope via LDS transpose.
template<int XK, bool IS_DEC>
__device__ void gru_tile(const int* __restrict__ sperm, const int jb, const int tid,
    const unsigned short* __restrict__ h_bf, unsigned short* __restrict__ ho_bf,
    const unsigned short* __restrict__ Whh_b, const unsigned short* __restrict__ Wih_b,
    const unsigned short* __restrict__ x_bf,
    const float* __restrict__ bih, const float* __restrict__ bhh,
    const int* __restrict__ endv, unsigned short* __restrict__ hf_bf,
    int t, f32x4 (&red)[2][4][64], unsigned short* hstage, f32x4& hold)
{
    const int lane = tid & 63, w = tid >> 6;
    const int nh = w & 1, kh = w >> 1;
    const int m = lane & 15, quad = lane >> 4;
    const int jcol = jb + m;

    stage_h32p(h_bf, sperm, hstage, tid);
    __syncthreads();

    f32x4 accr{}, accz{}, acchn{}, accxn{};

    {   // hidden: K = 1024, 32 chunks, split 16/16 across kh; A from LDS
        const int arow = (nh * 16 + m) * HRS + quad * 8;
        const unsigned short* brp = Whh_b + (size_t)(0 * LL + jcol) * LL + quad * 8;
        const unsigned short* bzp = Whh_b + (size_t)(1 * LL + jcol) * LL + quad * 8;
        const unsigned short* bnp = Whh_b + (size_t)(2 * LL + jcol) * LL + quad * 8;
        #pragma unroll 4
        for (int c = kh * 16; c < kh * 16 + 16; ++c) {
            const int k0 = c * 32;
            bf16x8 av = *(const bf16x8*)&hstage[arow + k0];
            bf16x8 br = *(const bf16x8*)(brp + k0);
            bf16x8 bz = *(const bf16x8*)(bzp + k0);
            bf16x8 bn = *(const bf16x8*)(bnp + k0);
            accr  = __builtin_amdgcn_mfma_f32_16x16x32_bf16(av, br, accr, 0, 0, 0);
            accz  = __builtin_amdgcn_mfma_f32_16x16x32_bf16(av, bz, accz, 0, 0, 0);
            acchn = __builtin_amdgcn_mfma_f32_16x16x32_bf16(av, bn, acchn, 0, 0, 0);
        }
    }
    {   // input: K = XK (enc 160, dec 32); read-only -> plain L1/L2-cached loads
        const int XC = XK / 32, XC0 = (XC + 1) / 2;
        const size_t xstride = IS_DEC ? (size_t)(50 * AA) : (size_t)(TT * (SS + AA));
        const int nphys = sperm[nh * 16 + m];
        const unsigned short* xp  = x_bf + (size_t)nphys * xstride + (size_t)t * XK + quad * 8;
        const unsigned short* brp = Wih_b + (size_t)(0 * LL + jcol) * XK + quad * 8;
        const unsigned short* bzp = Wih_b + (size_t)(1 * LL + jcol) * XK + quad * 8;
        const unsigned short* bnp = Wih_b + (size_t)(2 * LL + jcol) * XK + quad * 8;
        #pragma unroll
        for (int c = (kh ? XC0 : 0); c < (kh ? XC : XC0); ++c) {
            const int k0 = c * 32;
            bf16x8 av = *(const bf16x8*)(xp + k0);
            bf16x8 br = *(const bf16x8*)(brp + k0);
            bf16x8 bz = *(const bf16x8*)(bzp + k0);
            bf16x8 bn = *(const bf16x8*)(bnp + k0);
            accr  = __builtin_amdgcn_mfma_f32_16x16x32_bf16(av, br, accr, 0, 0, 0);
            accz  = __builtin_amdgcn_mfma_f32_16x16x32_bf16(av, bz, accz, 0, 0, 0);
            accxn = __builtin_amdgcn_mfma_f32_16x16x32_bf16(av, bn, accxn, 0, 0, 0);
        }
    }
    if (kh == 1) {
        red[nh][0][lane] = accr;  red[nh][1][lane] = accz;
        red[nh][2][lane] = acchn; red[nh][3][lane] = accxn;
    }
    __syncthreads();
    if (kh == 0) {
        accr  += red[nh][0][lane];  accz  += red[nh][1][lane];
        acchn += red[nh][2][lane];  accxn += red[nh][3][lane];
        const float br_  = bih[jcol] + bhh[jcol];
        const float bz_  = bih[LL + jcol] + bhh[LL + jcol];
        const float bxn_ = bih[2 * LL + jcol];
        const float bhn_ = bhh[2 * LL + jcol];
        unsigned short* tr = hstage + nh * (16 * 24);    // wave-private transpose scratch
        #pragma unroll
        for (int i = 0; i < 4; ++i) {
            const int n = sperm[nh * 16 + quad * 4 + i]; // C layout: row=quad*4+i, col=m
            float r = sigmoidf_(accr[i] + br_);
            float z = sigmoidf_(accz[i] + bz_);
            float g = tanhf(accxn[i] + bxn_ + r * (acchn[i] + bhn_));
            float hn = (1.0f - z) * g + z * hold[i];
            hold[i] = hn;
            unsigned short hb = f2bf(hn);
            tr[(quad * 4 + i) * 24 + m] = hb;            // LDS transpose (wave-lockstep)
            if (!IS_DEC) { if (endv[n] == t) st2(hf_bf + (size_t)n * LL + jcol, hb); }
        }
        // coalesced 16B n-major stores: lanes 0..31 each store 8 bf16
        if (lane < 32) {
            const int nl = lane >> 1, jh = lane & 1;
            bf16x8 vv = *(const bf16x8*)&tr[nl * 24 + jh * 8];
            stg16(ho_bf + (size_t)sperm[nh * 16 + nl] * LL + jb + jh * 8, vv);
        }
    }
}

// ---------------------------------------------------------------- reparametrize tile
__device__ void emb_tile(const PParams& P, const int* __restrict__ sperm, const int jb,
                         const int tid, f32x4 (&red)[2][4][64], unsigned short* hstage,
                         f32x4& hold)
{
    const int lane = tid & 63, w = tid >> 6;
    const int nh = w & 1, kh = w >> 1;
    const int m = lane & 15, quad = lane >> 4;
    const int jcol = jb + m;

    stage_h32p(P.hf_bf, sperm, hstage, tid);
    __syncthreads();

    f32x4 accm{}, accl{};
    const int arow = (nh * 16 + m) * HRS + quad * 8;
    const unsigned short* bmp = P.mlW_b + (size_t)jcol * LL + quad * 8;
    const unsigned short* blp = P.mlW_b + (size_t)(LL + jcol) * LL + quad * 8;
    #pragma unroll 4
    for (int c = kh * 16; c < kh * 16 + 16; ++c) {
        const int k0 = c * 32;
        bf16x8 av = *(const bf16x8*)&hstage[arow + k0];
        bf16x8 bm = *(const bf16x8*)(bmp + k0);
        bf16x8 bl = *(const bf16x8*)(blp + k0);
        accm = __builtin_amdgcn_mfma_f32_16x16x32_bf16(av, bm, accm, 0, 0, 0);
        accl = __builtin_amdgcn_mfma_f32_16x16x32_bf16(av, bl, accl, 0, 0, 0);
    }
    if (kh == 1) { red[nh][0][lane] = accm; red[nh][1][lane] = accl; }
    __syncthreads();
    if (kh == 0) {
        accm += red[nh][0][lane]; accl += red[nh][1][lane];
        unsigned short* tr = hstage + nh * (16 * 24);
        #pragma unroll
        for (int i = 0; i < 4; ++i) {
            const int n = sperm[nh * 16 + quad * 4 + i];
            float mu = accm[i] + P.mub[jcol];
            float lv = accl[i] + P.lvb[jcol];
            float e = mu + expf(0.5f * lv) * P.eps[(size_t)n * LL + jcol];
            hold[i] = e;
            tr[(quad * 4 + i) * 24 + m] = f2bf(e);
        }
        if (lane < 32) {
            const int nl = lane >> 1, jh = lane & 1;
            bf16x8 vv = *(const bf16x8*)&tr[nl * 24 + jh * 8];
            stg16(P.hdecAb + (size_t)sperm[nh * 16 + nl] * LL + jb + jh * 8, vv);
        }
    }
}

// ---------------------------------------------------------------- MFMA decoder head
// Two blocks per group, 16 (permuted) samples each. sperm16 = sperm + 16*(lbid-64).
__device__ void head_tile(const PParams& P, const int* __restrict__ sperm16, const int tid,
                          const unsigned short* __restrict__ h_bf, int ti,
                          unsigned short* hstage, char* shu)
{
    auto& ylds  = *(unsigned short (*)[16][136])(shu);
    auto& y2lds = *(unsigned short (*)[16][72])(shu + 4352);
    float* lred = (float*)(shu + 4352 + 2304);
    const int lane = tid & 63, w = tid >> 6;
    const int m16 = lane & 15, quad = lane >> 4;

    stage_h16p(h_bf, sperm16, hstage, tid);
    __syncthreads();

    // ---- y1: K=1024, 8 j-tiles, wave w -> {2w, 2w+1}
    #pragma unroll
    for (int jt = 0; jt < 2; ++jt) {
        const int c0 = (w * 2 + jt) * 16;
        f32x4 acc{};
        const int abase = m16 * HRS + quad * 8;
        const unsigned short* bp = P.d1Wb + (size_t)(c0 + m16) * LL + quad * 8;
        #pragma unroll 4
        for (int c = 0; c < 32; ++c) {
            bf16x8 av = *(const bf16x8*)&hstage[abase + c * 32];
            bf16x8 bv = *(const bf16x8*)(bp + c * 32);
            acc = __builtin_amdgcn_mfma_f32_16x16x32_bf16(av, bv, acc, 0, 0, 0);
        }
        const float b = P.d1b[c0 + m16];
        #pragma unroll
        for (int i = 0; i < 4; ++i)
            ylds[quad * 4 + i][c0 + m16] = f2bf(fmaxf(acc[i] + b, 0.0f));
    }
    __syncthreads();

    // ---- y2: K=128, wave w -> tile w
    {
        const int c0 = w * 16;
        f32x4 acc{};
        #pragma unroll
        for (int c = 0; c < 4; ++c) {
            bf16x8 av = *(const bf16x8*)&ylds[m16][c * 32 + quad * 8];
            bf16x8 bv = *(const bf16x8*)(P.d2Wb + (size_t)(c0 + m16) * 128 + c * 32 + quad * 8);
            acc = __builtin_amdgcn_mfma_f32_16x16x32_bf16(av, bv, acc, 0, 0, 0);
        }
        const float b = P.d2b[c0 + m16];
        #pragma unroll
        for (int i = 0; i < 4; ++i)
            y2lds[quad * 4 + i][c0 + m16] = f2bf(fmaxf(acc[i] + b, 0.0f));
    }
    __syncthreads();

    // ---- y3: K=64, wave w -> {2w, 2w+1}; fused masked L1
    float lsum = 0.0f;
    #pragma unroll
    for (int jt = 0; jt < 2; ++jt) {
        const int c0 = (w * 2 + jt) * 16;
        f32x4 acc{};
        #pragma unroll
        for (int c = 0; c < 2; ++c) {
            bf16x8 av = *(const bf16x8*)&y2lds[m16][c * 32 + quad * 8];
            bf16x8 bv = *(const bf16x8*)(P.d3Wb + (size_t)(c0 + m16) * 64 + c * 32 + quad * 8);
            acc = __builtin_amdgcn_mfma_f32_16x16x32_bf16(av, bv, acc, 0, 0, 0);
        }
        const int col = c0 + m16;
        const float b = P.d3b[col];
        #pragma unroll
        for (int i = 0; i < 4; ++i) {
            const int n = sperm16[quad * 4 + i];
            if (ti < P.limitv[n]) {
                int trw = ti + P.startv[n]; if (trw >= TT) trw -= TT;
                float v = P.s_next[(size_t)n * TT * SS + (size_t)trw * SS + col];
                lsum += fabsf(v - (acc[i] + b));
            }
        }
    }
    for (int off = 32; off >= 1; off >>= 1) lsum += __shfl_down(lsum, off);
    if (lane == 0) lred[w] = lsum;
    __syncthreads();
    if (tid == 0) atomicAdd(P.loss, lred[0] + lred[1] + lred[2] + lred[3]);
}

// ---------------------------------------------------------------- the persistent kernel
__global__ __launch_bounds__(256, 2)
void persist(PParams P)
{
    __shared__ __align__(16) unsigned short hstage[32 * HRS];   // 66176 B
    __shared__ __align__(16) char shu[8192];                    // red OR head ylds/y2lds/lred OR sort keys
    __shared__ int sperm[32];                                   // group's permuted sample ids
    __shared__ int mint, sME, sML, sbrk;
    f32x4 (&red)[2][4][64] = *(f32x4 (*)[2][4][64])(shu);
    const int bid = blockIdx.x, tid = threadIdx.x;
    const int g = bid & 3, lbid = bid >> 2;    // group g; lbid 0..63 matmul, 64..65 head
    const int jb = lbid * 16;                  // matmul blocks only (lbid < 64)
    int* gb = P.bar + 4608 + g * 128;          // group barrier state (512 B apart)
    int* brk = P.bar + 132;

    // ================= phase 0: cast (plain stores), split detection, h0, adec
    {
        const long N0 = 3072L * 160, N1 = N0 + 3072L * 1024, N2 = N1 + 3072L * 32,
                   N3 = N2 + 3072L * 1024, N4 = N3 + 1048576L, N5 = N4 + 1048576L,
                   N6 = N5 + 128L * 100 * 160, N7 = N6 + 131072L, N8 = N7 + 8192L,
                   N9 = N8 + 8192L;
        for (long i = (long)bid * 256 + tid; i < N9; i += (long)NBLK * 256) {
            if (i < N0)      P.eWih_b[i]      = f2bf(P.eWih[i]);
            else if (i < N1) P.eWhh_b[i - N0] = f2bf(P.eWhh[i - N0]);
            else if (i < N2) P.dWih_b[i - N1] = f2bf(P.dWih[i - N1]);
            else if (i < N3) P.dWhh_b[i - N2] = f2bf(P.dWhh[i - N2]);
            else if (i < N4) P.mlW_b[i - N3]  = f2bf(P.muW[i - N3]);
            else if (i < N5) P.mlW_b[1048576L + (i - N4)] = f2bf(P.lvW[i - N4]);
            else if (i < N6) {
                long j = i - N5;                  // n*16000 + t*160 + k
                int  k = (int)(j % 160);
                long nt = j / 160;
                int  t = (int)(nt % 100), n = (int)(nt / 100);
                float v = (k < SS) ? P.s[(size_t)n * TT * SS + (size_t)t * SS + k]
                                   : P.a[(size_t)n * TT * AA + (size_t)t * AA + (k - SS)];
                P.xenc_b[j] = f2bf(v);
            }
            else if (i < N7) P.d1Wb[i - N6] = f2bf(P.d1W[i - N6]);
            else if (i < N8) P.d2Wb[i - N7] = f2bf(P.d2W[i - N7]);
            else             P.d3Wb[i - N8] = f2bf(P.d3W[i - N8]);
        }
    }
    if (bid < NN_) {
        const int n = bid;
        if (tid == 0) mint = TT - 1;
        __syncthreads();
        int t = tid + 1;
        if (t < TT && tid < 128) {
            const float* row = P.s + (size_t)n * TT * SS + (size_t)t * SS;
            bool allz = true;
            for (int i = 0; i < SS; ++i) { if (row[i] != 0.0f) { allz = false; break; } }
            if (allz) atomicMin(&mint, t);
        }
        __syncthreads();
        const int m = mint, st = m + 1;
        if (tid == 0) { P.endv[n] = m - 1; P.startv[n] = st; P.limitv[n] = TT - 1 - m; }
        for (int idx = tid; idx < LL; idx += 256)
            P.hencAb[(size_t)n * LL + idx] = 0x3F80;   // bf16 1.0
        for (int idx = tid; idx < 50 * AA; idx += 256) {
            int i = idx >> 5, k = idx & 31;
            int tr = i + st; if (tr >= TT) tr -= TT;
            P.adec_b[(size_t)n * (50 * AA) + idx] =
                f2bf(P.a[(size_t)n * TT * AA + (size_t)tr * AA + k]);
        }
    }
    // one-time global heavy barrier: flush phase-0 plain stores, drop stale lines
    __syncthreads();
    if (tid == 0) __threadfence();
    gbar_global(P.bar, bid, tid, 1);
    if (tid == 0) __threadfence();
    __syncthreads();

    // ================= length-sorted permutation (identical in every block)
    {
        int* keys = (int*)shu;
        if (tid < 128) keys[tid] = P.endv[tid];
        if (tid == 0) sbrk = 0;
        __syncthreads();
        if (tid < 128) {
            const int k = keys[tid];
            int r = 0;
            for (int j = 0; j < 128; ++j) {
                const int kj = keys[j];
                r += (kj < k) | ((kj == k) & (j < tid));
            }
            if (r >= g * 32 && r < g * 32 + 32) sperm[r - g * 32] = tid;  // rank -> sample
        }
        __syncthreads();
    }

    // ================= group ME = max(end), ML = max(limit) over its 32 samples
    int ME, ML;
    {
        int lv = 0, ev = 0;
        if (tid < 32) { const int n = sperm[tid]; lv = P.limitv[n]; ev = P.endv[n]; }
        if (tid < 64) {
            for (int off = 16; off >= 1; off >>= 1) {
                lv = max(lv, __shfl_down(lv, off));
                ev = max(ev, __shfl_down(ev, off));
            }
            if (tid == 0) { sML = lv; sME = ev; }
        }
        __syncthreads();
        ML = sML; ME = sME;
        __syncthreads();
    }

    f32x4 hold = { 1.0f, 1.0f, 1.0f, 1.0f };   // enc h0 = ones (fp32 state lives here)
    int ggen = 0;

    // ================= encoder: t = 0..ME_g
    for (int t = 0; t <= ME; ++t) {
        if (lbid < 64) {
            const unsigned short* hib = (t & 1) ? P.hencBb : P.hencAb;
            unsigned short*       hob = (t & 1) ? P.hencAb : P.hencBb;
            gru_tile<160, false>(sperm, jb, tid, hib, hob,
                                 P.eWhh_b, P.eWih_b, P.xenc_b, P.ebih, P.ebhh,
                                 P.endv, P.hf_bf, t, red, hstage, hold);
        }
        gbar_group(gb, brk, lbid, tid, ++ggen, &sbrk);
    }

    // ================= reparametrize (deposits decoder h0 into hold regs)
    if (lbid < 64) emb_tile(P, sperm, jb, tid, red, hstage, hold);
    gbar_group(gb, brk, lbid, tid, ++ggen, &sbrk);

    // ================= decoder: i = 0..ML_g; matmul (i<ML) overlaps head for step i-1
    for (int i = 0; i <= ML; ++i) {
        const unsigned short* hib = (i & 1) ? P.hdecBb : P.hdecAb;
        if (lbid < 64) {
            if (i < ML) {
                unsigned short* hob = (i & 1) ? P.hdecAb : P.hdecBb;
                gru_tile<32, true>(sperm, jb, tid, hib, hob,
                                   P.dWhh_b, P.dWih_b, P.adec_b, P.dbih, P.dbhh,
                                   nullptr, nullptr, i, red, hstage, hold);
            }
        } else if (i >= 1) {
            head_tile(P, sperm + (lbid - 64) * 16, tid, hib, i - 1, hstage, shu);
        }
        gbar_group(gb, brk, lbid, tid, ++ggen, &sbrk);
    }
}

// ---------------------------------------------------------------- launch
extern "C" void kernel_launch(void* const* d_in, const int* in_sizes, int n_in,
                              void* d_out, int out_size, void* d_ws, size_t ws_size,
                              hipStream_t stream) {
    PParams P;
    P.s      = (const float*)d_in[0];
    P.a      = (const float*)d_in[1];
    P.s_next = (const float*)d_in[3];
    P.eps    = (const float*)d_in[4];
    P.eWih   = (const float*)d_in[5];
    P.eWhh   = (const float*)d_in[6];
    P.ebih   = (const float*)d_in[7];
    P.ebhh   = (const float*)d_in[8];
    P.muW    = (const float*)d_in[9];
    P.mub    = (const float*)d_in[10];
    P.lvW    = (const float*)d_in[11];
    P.lvb    = (const float*)d_in[12];
    // st1..st3 (13..18) dead code w.r.t. the loss
    P.dWih   = (const float*)d_in[19];
    P.dWhh   = (const float*)d_in[20];
    P.dbih   = (const float*)d_in[21];
    P.dbhh   = (const float*)d_in[22];
    P.d1W    = (const float*)d_in[23];
    P.d1b    = (const float*)d_in[24];
    P.d2W    = (const float*)d_in[25];
    P.d2b    = (const float*)d_in[26];
    P.d3W    = (const float*)d_in[27];
    P.d3b    = (const float*)d_in[28];
    P.loss   = (float*)d_out;

    char* p = (char*)d_ws;
    P.bar    = (int*)p;                    p += 24576;   // 6144 ints (barriers)
    P.endv   = (int*)p;                    p += 512;
    P.startv = (int*)p;                    p += 512;
    P.limitv = (int*)p;                    p += 512;
    p += 2560;                             // pad
    P.hencAb = (unsigned short*)p;         p += 128 * 1024 * 2;
    P.hencBb = (unsigned short*)p;         p += 128 * 1024 * 2;
    P.hdecAb = (unsigned short*)p;         p += 128 * 1024 * 2;
    P.hdecBb = (unsigned short*)p;         p += 128 * 1024 * 2;
    P.hf_bf  = (unsigned short*)p;         p += 128 * 1024 * 2;
    P.eWih_b = (unsigned short*)p;         p += 3072 * 160 * 2;
    P.eWhh_b = (unsigned short*)p;         p += 3072 * 1024 * 2;
    P.dWih_b = (unsigned short*)p;         p += 3072 * 32 * 2;
    P.dWhh_b = (unsigned short*)p;         p += 3072 * 1024 * 2;
    P.mlW_b  = (unsigned short*)p;         p += 2048 * 1024 * 2;
    P.xenc_b = (unsigned short*)p;         p += 128 * 100 * 160 * 2;
    P.adec_b = (unsigned short*)p;         p += 128 * 50 * 32 * 2;
    P.d1Wb   = (unsigned short*)p;         p += 128 * 1024 * 2;
    P.d2Wb   = (unsigned short*)p;         p += 64 * 128 * 2;
    P.d3Wb   = (unsigned short*)p;         p += 128 * 64 * 2;

    hipLaunchKernelGGL(init_kernel, dim3(1), dim3(256), 0, stream, P.bar, P.loss);
    hipLaunchKernelGGL(persist, dim3(NBLK), dim3(256), 0, stream, P);
}